// Round 1
// baseline (27.807 us; speedup 1.0000x reference)
//
#include <hip/hip_runtime.h>

// CP_Based: out[b,u] = (prod_f rsqrt(1+X^2)) * sum_r prod_f (k0[r,f,u] + X[b,f]*k1[r,f,u])
// X: [B,32] f32, kernel: [2,10,32,8] f32, out: [B,8] f32

typedef float f32x2 __attribute__((ext_vector_type(2)));
typedef float f32x4 __attribute__((ext_vector_type(4)));

#define F 32
#define RANK 10
#define UNITS 8

__global__ __launch_bounds__(256) void cp_based_kernel(
    const float* __restrict__ X,
    const float* __restrict__ K,   // [2,10,32,8] flat
    float* __restrict__ out,
    int B)
{
    int b = blockIdx.x * blockDim.x + threadIdx.x;
    if (b >= B) return;

    // ---- load X row (8 x float4, 16B per lane) and compute p0 = prod rsqrt(1+x^2)
    const f32x4* xrow = reinterpret_cast<const f32x4*>(X + (size_t)b * F);
    float xv[F];
    float p0 = 1.0f;
#pragma unroll
    for (int i = 0; i < F / 4; ++i) {
        f32x4 v = xrow[i];
#pragma unroll
        for (int j = 0; j < 4; ++j) {
            float x = v[j];
            xv[i * 4 + j] = x;
            p0 *= __builtin_amdgcn_rsqf(__builtin_fmaf(x, x, 1.0f));
        }
    }

    // K layout: flat idx = ((d*RANK + r)*F + f)*UNITS + u
    // k0 block at offset 0, k1 block at offset RANK*F*UNITS
    const int K1_OFF = RANK * F * UNITS;

    f32x2 acc0 = {0.f, 0.f}, acc1 = {0.f, 0.f}, acc2 = {0.f, 0.f}, acc3 = {0.f, 0.f};

    for (int r = 0; r < RANK; ++r) {
        f32x2 p0v = {1.f, 1.f}, p1v = {1.f, 1.f}, p2v = {1.f, 1.f}, p3v = {1.f, 1.f};
        const float* k0base = K + (size_t)(r * F) * UNITS;
        const float* k1base = K + (size_t)K1_OFF + (size_t)(r * F) * UNITS;
#pragma unroll
        for (int f = 0; f < F; ++f) {
            const f32x2* k0 = reinterpret_cast<const f32x2*>(k0base + f * UNITS);
            const f32x2* k1 = reinterpret_cast<const f32x2*>(k1base + f * UNITS);
            float xf = xv[f];
            f32x2 xs = {xf, xf};
            // t = k0 + x*k1  (packed fma), prod *= t (packed mul)
            f32x2 t0 = xs * k0[0 + 0] * 0.0f; // placeholder removed below
            (void)t0;
            {
                f32x2 ta = xs * k1[0] + k0[0];
                f32x2 tb = xs * k1[1] + k0[1];
                f32x2 tc = xs * k1[2] + k0[2];
                f32x2 td = xs * k1[3] + k0[3];
                p0v *= ta;
                p1v *= tb;
                p2v *= tc;
                p3v *= td;
            }
        }
        acc0 += p0v;
        acc1 += p1v;
        acc2 += p2v;
        acc3 += p3v;
    }

    acc0 *= p0; acc1 *= p0; acc2 *= p0; acc3 *= p0;

    float* o = out + (size_t)b * UNITS;
    f32x4 r0 = {acc0[0], acc0[1], acc1[0], acc1[1]};
    f32x4 r1 = {acc2[0], acc2[1], acc3[0], acc3[1]};
    reinterpret_cast<f32x4*>(o)[0] = r0;
    reinterpret_cast<f32x4*>(o)[1] = r1;
}

extern "C" void kernel_launch(void* const* d_in, const int* in_sizes, int n_in,
                              void* d_out, int out_size, void* d_ws, size_t ws_size,
                              hipStream_t stream) {
    const float* X = (const float*)d_in[0];
    const float* K = (const float*)d_in[1];
    float* out = (float*)d_out;
    int B = in_sizes[0] / F;  // 131072

    dim3 block(256);
    dim3 grid((B + 255) / 256);
    hipLaunchKernelGGL(cp_based_kernel, grid, block, 0, stream, X, K, out, B);
}